// Round 17
// baseline (372.050 us; speedup 1.0000x reference)
//
#include <hip/hip_runtime.h>

typedef __attribute__((ext_vector_type(8))) _Float16 half8;
typedef __attribute__((ext_vector_type(4))) _Float16 half4;
typedef __attribute__((ext_vector_type(4))) float f32x4;

#define MFMA16(a, b, c) __builtin_amdgcn_mfma_f32_16x16x32_f16((a), (b), (c), 0, 0, 0)
#define MFMA16K16(a, b, c) __builtin_amdgcn_mfma_f32_16x16x16f16((a), (b), (c), 0, 0, 0)

#define WAITV(N) asm volatile("s_waitcnt vmcnt(" #N ") lgkmcnt(0)" ::: "memory")
#define WAITL()  asm volatile("s_waitcnt lgkmcnt(0)" ::: "memory")
#define SBAR()   asm volatile("s_barrier" ::: "memory")

// B=8, L=128, N=64, D=256, H=8, dk=32.  M = 65536 tokens.
// Token orders: LN = (b,l,n), NL = (b,n,l).

__device__ inline int map_ln_nl(int t) {   // (b,l,n) -> (b,n,l)
    return (t & ~8191) | ((t & 63) << 7) | ((t >> 6) & 127);
}

typedef const __attribute__((address_space(1))) unsigned int guint;
typedef __attribute__((address_space(3))) unsigned int luint;
__device__ inline void gld16(const _Float16* g, _Float16* l) {
    __builtin_amdgcn_global_load_lds((guint*)g, (luint*)l, 16, 0, 0);
}

// ---------------- weight prep (single dispatch): fp32->fp16 cvt + W2/b2 ----------------
// slots: 0=t_wq 1=t_wk 2=s_wk 3=t_wv 4=s_wv 5=W2 6=s_wd
__global__ __launch_bounds__(256) void prep_weights(
    const float* __restrict__ t_wq, const float* __restrict__ t_wk,
    const float* __restrict__ s_wk, const float* __restrict__ t_wv,
    const float* __restrict__ s_wv, const float* __restrict__ s_wd,
    const float* __restrict__ s_wq, const float* __restrict__ t_wd,
    const float* __restrict__ t_bd, _Float16* __restrict__ Wb,
    float* __restrict__ b2)
{
    const int bx = blockIdx.x;
    if (bx < 1536) {
        const float* src[6] = {t_wq, t_wk, s_wk, t_wv, s_wv, s_wd};
        const int m = bx >> 8;
        const int slot = (m < 5) ? m : 6;
        const int i = (bx & 255) * 256 + threadIdx.x;
        Wb[(size_t)slot * 65536 + i] = (_Float16)src[m][i];
    } else {
        const int e = bx - 1536;
        const int d = threadIdx.x;
        float acc = 0.0f;
        for (int c = 0; c < 256; ++c)
            acc = fmaf(s_wq[e * 256 + c], t_wd[c * 256 + d], acc);
        Wb[5 * 65536 + e * 256 + d] = (_Float16)acc;
        if (d == 0) {
            float bb = 0.0f;
            for (int c = 0; c < 256; ++c) bb = fmaf(s_wq[e * 256 + c], t_bd[c], bb);
            b2[e] = bb;
        }
    }
}

// ---------------- penta GEMM v4: A-prefetch depth 3 ----------------
// 256 blocks x 10 jobs (R13 structure).  Only change vs R16: THREE A register
// sets, issueA(s+3) at step s, re-derived WAITV table.  FIFO trace (verified
// for all 40 steps): per step append [B(s+1), A(s+3)]; steady top =
// [A(s+1), B(s), A(s+2)] (12) -> +8 -> WAITV(12) retires {A(s+1), B(s)} so
// the end-of-step writeA's implicit wait is free.  Post-epilogue (s%4==0,
// s>0 and s==0): st8 in FIFO -> WAITV(16).  Tail: s=37 -> 8, s=38 -> 4,
// s=39 -> 0.
__global__ __launch_bounds__(512, 2) void gemm_penta(
    const float* __restrict__ q, const float* __restrict__ k,
    const float* __restrict__ v, const _Float16* __restrict__ Wb,
    _Float16* __restrict__ Qt, _Float16* __restrict__ Kt,
    _Float16* __restrict__ Vt, _Float16* __restrict__ Ks,
    _Float16* __restrict__ Vs)
{
    __shared__ __align__(16) _Float16 lds[66048];

    const int tid  = threadIdx.x;
    const int lane = tid & 63;
    const int l15  = lane & 15;
    const int lhi  = lane >> 4;
    const int wid  = tid >> 6;
    const int bid  = blockIdx.x;
    const int wr   = (wid >> 2) * 64;
    const int wc   = (wid & 3) * 64;

    int rA[2], cA[2];
#pragma unroll
    for (int i = 0; i < 2; ++i) {
        const int c = i * 512 + tid;
        rA[i] = c >> 3; cA[i] = ((c & 7) ^ (rA[i] & 7)) * 8;
    }
    int rB[4], cB[4];
#pragma unroll
    for (int i = 0; i < 4; ++i) {
        const int c = i * 512 + tid;
        rB[i] = c >> 3; cB[i] = ((c & 7) ^ (rB[i] & 7)) * 8;
    }

    f32x4 ar0[2][2], ar1[2][2], ar2[2][2];   // three A staging sets

    auto issueA = [&](int s, f32x4 (&dst)[2][2]) {
        const int jj = s >> 2;
        const int w  = jj - (jj / 5) * 5;
        const float* A = (w == 0) ? q : (w < 3 ? k : v);
        const int m0 = (2 * bid + jj / 5) * 128;
        const int k0 = (s & 3) * 64;
#pragma unroll
        for (int i = 0; i < 2; ++i) {
            const float* p = A + (size_t)(m0 + rA[i]) * 256 + k0 + cA[i];
            dst[i][0] = *(const f32x4*)(p);
            dst[i][1] = *(const f32x4*)(p + 4);
        }
    };
    auto issueA3 = [&](int s) {       // issue A(s) into set s%3
        const int r = s - (s / 3) * 3;
        if (r == 0)      issueA(s, ar0);
        else if (r == 1) issueA(s, ar1);
        else             issueA(s, ar2);
    };
    auto stageB = [&](int s) {
        const int jj = s >> 2;
        const _Float16* W = Wb + (size_t)(jj - (jj / 5) * 5) * 65536;
        _Float16* Bd = lds + 16384 + (s & 1) * 16384;
        const int k0 = (s & 3) * 64;
#pragma unroll
        for (int i = 0; i < 4; ++i)
            gld16(W + (size_t)rB[i] * 256 + k0 + cB[i], Bd + (i * 512 + tid) * 8);
    };
    auto writeA = [&](int s, const f32x4 (&src)[2][2]) {
        _Float16* Ad = lds + (s & 1) * 8192;
#pragma unroll
        for (int i = 0; i < 2; ++i) {
            half8 h;
#pragma unroll
            for (int r2 = 0; r2 < 4; ++r2) {
                h[r2]     = (_Float16)src[i][0][r2];
                h[4 + r2] = (_Float16)src[i][1][r2];
            }
            *(half8*)(Ad + (i * 512 + tid) * 8) = h;
        }
    };
    auto writeA3 = [&](int s) {       // write A(s) from set s%3 into A-buf s&1
        const int r = s - (s / 3) * 3;
        if (r == 0)      writeA(s, ar0);
        else if (r == 1) writeA(s, ar1);
        else             writeA(s, ar2);
    };

    f32x4 acc[4][4] = {};

    auto mfmaStep = [&](int s) {
        const _Float16* Ab = lds + (s & 1) * 8192;
        const _Float16* Bb = lds + 16384 + (s & 1) * 16384;
#pragma unroll
        for (int kk = 0; kk < 2; ++kk) {
            half8 af[4], bf[4];
#pragma unroll
            for (int mi = 0; mi < 4; ++mi) {
                const int R = wr + mi * 16 + l15;
                af[mi] = *(const half8*)(Ab + R * 64 + (((kk * 4 + lhi) ^ (R & 7)) * 8));
            }
#pragma unroll
            for (int nj = 0; nj < 4; ++nj) {
                const int R = wc + nj * 16 + l15;
                bf[nj] = *(const half8*)(Bb + R * 64 + (((kk * 4 + lhi) ^ (R & 7)) * 8));
            }
#pragma unroll
            for (int mi = 0; mi < 4; ++mi)
#pragma unroll
                for (int nj = 0; nj < 4; ++nj)
                    acc[mi][nj] = MFMA16(af[mi], bf[nj], acc[mi][nj]);
        }
    };

    auto epilogue = [&](int jj) {
        const int w = jj - (jj / 5) * 5;
        _Float16* Cp; bool nl;
        if (w == 0)      { Cp = Qt; nl = true;  }
        else if (w == 1) { Cp = Kt; nl = true;  }
        else if (w == 2) { Cp = Ks; nl = false; }
        else if (w == 3) { Cp = Vt; nl = true;  }
        else             { Cp = Vs; nl = false; }
        const int m0 = (2 * bid + jj / 5) * 128;
        _Float16* Cst = lds + 49152;
#pragma unroll
        for (int c = 0; c < 2; ++c) {
            if ((wid >> 2) == c) {
#pragma unroll
                for (int mi = 0; mi < 4; ++mi)
#pragma unroll
                    for (int nj = 0; nj < 4; ++nj) {
                        const int col = wc + nj * 16 + l15;
#pragma unroll
                        for (int j = 0; j < 4; ++j)
                            Cst[(mi * 16 + lhi * 4 + j) * 264 + col] =
                                (_Float16)acc[mi][nj][j];
                    }
            }
            WAITL(); SBAR();
            const int r  = tid >> 3;
            const int c0 = (tid & 7) * 32;
            const int grow = m0 + c * 64 + r;
            const int orow = nl ? map_ln_nl(grow) : grow;
            _Float16* dst = Cp + (size_t)orow * 256 + c0;
            const _Float16* sp = Cst + r * 264 + c0;
#pragma unroll
            for (int u = 0; u < 4; ++u)
                *(half8*)(dst + u * 8) = *(const half8*)(sp + u * 8);
            WAITL(); SBAR();
        }
#pragma unroll
        for (int mi = 0; mi < 4; ++mi)
#pragma unroll
            for (int nj = 0; nj < 4; ++nj)
                acc[mi][nj] = (f32x4){0.f, 0.f, 0.f, 0.f};
    };

    // prologue: A0->set0, B0, A1->set1, A2->set2, A0->LDS (implicit wait A0)
    issueA(0, ar0); stageB(0); issueA(1, ar1); issueA(2, ar2); writeA(0, ar0);

    for (int t = 0; t < 20; ++t) {
        {   // even step s = 2t  (s%4 == 0 or 2)
            const int s = 2 * t;
            if (s + 1 < 40) stageB(s + 1);
            if (s + 3 < 40) issueA3(s + 3);
            if (s == 38)            { WAITV(4);  }
            else if ((s & 3) == 0)  { WAITV(16); }   // incl. s=0
            else                    { WAITV(12); }
            SBAR();
            mfmaStep(s);
            SBAR();
            if (s + 1 < 40) writeA3(s + 1);
        }
        {   // odd step s = 2t+1  (s%4 == 1 or 3)
            const int s = 2 * t + 1;
            if (s + 1 < 40) stageB(s + 1);
            if (s + 3 < 40) issueA3(s + 3);
            if (s == 39)      { WAITV(0); }
            else if (s == 37) { WAITV(8); }
            else              { WAITV(12); }
            SBAR();
            mfmaStep(s);
            SBAR();
            if (s + 1 < 40) writeA3(s + 1);
            if ((s & 3) == 3) epilogue(s >> 2);
        }
    }
}

// ---------------- temporal attention: per (b,n,h), seq = L = 128, NL layout ----------------
// XCD-swizzled blockIdx (bijective, 4096 = 8*512).
__global__ __launch_bounds__(256) void attn_temporal(
    const _Float16* __restrict__ Q, const _Float16* __restrict__ K,
    const _Float16* __restrict__ V, _Float16* __restrict__ O)
{
    __shared__ __align__(16) _Float16 Vt[32][136];   // V^T: [d][l]

    const int tid  = threadIdx.x;
    const int lane = tid & 63;
    const int l15  = lane & 15;
    const int lhi  = lane >> 4;
    const int wid  = tid >> 6;
    const int bidx = (blockIdx.x & 7) * 512 + (blockIdx.x >> 3);
    const int h = bidx & 7;
    const int n = (bidx >> 3) & 63;
    const int b = bidx >> 9;
    const size_t base = ((size_t)(b * 64 + n) * 128) * 256 + (size_t)h * 32;

    {
        const int l  = tid >> 1;
        const int dh = (tid & 1) * 16;
        const _Float16* srcp = V + base + (size_t)l * 256 + dh;
        half8 v0 = *(const half8*)(srcp);
        half8 v1 = *(const half8*)(srcp + 8);
#pragma unroll
        for (int j = 0; j < 8; ++j) {
            Vt[dh + j][l]     = v0[j];
            Vt[dh + 8 + j][l] = v1[j];
        }
    }
    __syncthreads();

    half8 qf[2];
#pragma unroll
    for (int ct = 0; ct < 2; ++ct)
        qf[ct] = *(const half8*)(Q + base +
                  (size_t)(wid * 32 + ct * 16 + l15) * 256 + lhi * 8);
    f32x4 st[2][8] = {};
#pragma unroll
    for (int rt = 0; rt < 8; ++rt) {
        half8 kf = *(const half8*)(K + base +
                    (size_t)(rt * 16 + l15) * 256 + lhi * 8);
#pragma unroll
        for (int ct = 0; ct < 2; ++ct)
            st[ct][rt] = MFMA16(kf, qf[ct], st[ct][rt]);
    }

    const float scale = 0.17677669529663687f;  // 1/sqrt(32)
#pragma unroll
    for (int ct = 0; ct < 2; ++ct) {
        float m = st[ct][0][0];
#pragma unroll
        for (int rt = 0; rt < 8; ++rt)
#pragma unroll
            for (int j = 0; j < 4; ++j) m = fmaxf(m, st[ct][rt][j]);
        m = fmaxf(m, __shfl_xor(m, 16));
        m = fmaxf(m, __shfl_xor(m, 32));
        float sum = 0.0f;
#pragma unroll
        for (int rt = 0; rt < 8; ++rt)
#pragma unroll
            for (int j = 0; j < 4; ++j) {
                const float p = __expf((st[ct][rt][j] - m) * scale);
                st[ct][rt][j] = p;
                sum += p;
            }
        sum += __shfl_xor(sum, 16);
        sum += __shfl_xor(sum, 32);
        const float inv = 1.0f / sum;
#pragma unroll
        for (int rt = 0; rt < 8; ++rt)
#pragma unroll
            for (int j = 0; j < 4; ++j) st[ct][rt][j] *= inv;
    }

    f32x4 o[2][2] = {};
#pragma unroll
    for (int rt = 0; rt < 8; ++rt) {
        half4 pa[2];
#pragma unroll
        for (int ct = 0; ct < 2; ++ct) {
            half4 tt;
#pragma unroll
            for (int j = 0; j < 4; ++j) tt[j] = (_Float16)st[ct][rt][j];
            pa[ct] = tt;
        }
#pragma unroll
        for (int dt = 0; dt < 2; ++dt) {
            half4 vb = *(const half4*)(&Vt[dt * 16 + l15][rt * 16 + lhi * 4]);
#pragma unroll
            for (int ct = 0; ct < 2; ++ct)
                o[ct][dt] = MFMA16K16(pa[ct], vb, o[ct][dt]);
        }
    }
#pragma unroll
    for (int ct = 0; ct < 2; ++ct)
#pragma unroll
        for (int dt = 0; dt < 2; ++dt)
#pragma unroll
            for (int j = 0; j < 4; ++j)
                O[base + (size_t)(wid * 32 + ct * 16 + lhi * 4 + j) * 256 +
                  dt * 16 + l15] = (_Float16)o[ct][dt][j];
}

// ---------------- fused social stage: per (b,l), 8 waves = 8 heads (R13) ----------------
__global__ __launch_bounds__(512, 4) void attn_social_fused(
    const _Float16* __restrict__ Ot,   // NL (b,n,l,d) fp16
    const _Float16* __restrict__ Ksrc, // LN fp16
    const _Float16* __restrict__ Vsrc, // LN fp16
    const _Float16* __restrict__ W2, const float* __restrict__ b2,
    const _Float16* __restrict__ Wd, const float* __restrict__ bd,
    float* __restrict__ out)           // LN fp32
{
    __shared__ __align__(16) _Float16 lds[18432];   // 36 KB

    const int tid  = threadIdx.x;
    const int lane = tid & 63;
    const int l15  = lane & 15;
    const int lhi  = lane >> 4;
    const int h    = tid >> 6;          // wave = head
    const int l = blockIdx.x & 127;
    const int b = blockIdx.x >> 7;

    _Float16* Ot_lds = lds;                        // [64][264]
    _Float16* Vt_h   = lds + h * 2304;             // [32][72] (after BAR2)
    _Float16* O_lds  = lds;                        // [64][264] (after BAR3)

    const size_t kvbase = ((size_t)(b * 128 + l) * 64) * 256;

    // P1: stage Ot slice (coalesced 512B rows)
#pragma unroll
    for (int i = 0; i < 4; ++i) {
        const int chunk = i * 512 + tid;
        const int r  = chunk >> 5;
        const int c8 = (chunk & 31) * 8;
        half8 vv = *(const half8*)(Ot + ((size_t)(b * 64 + r) * 128 + l) * 256 + c8);
        *(half8*)(Ot_lds + r * 264 + c8) = vv;
    }
    __syncthreads();                               // BAR1

    // P2: Qs = Ot @ W2_h^T + b2_h -> qh[mt][g] REGISTERS ONLY
    half4 qh[2][4];
    {
        f32x4 qacc[2][4] = {};
#pragma unroll
        for (int ks = 0; ks < 8; ++ks) {
            half8 wf[2], of[4];
#pragma unroll
            for (int mt = 0; mt < 2; ++mt)
                wf[mt] = *(const half8*)(W2 + (size_t)(h * 32 + mt * 16 + l15) * 256 + ks * 32 + lhi * 8);
#pragma unroll
            for (int tg = 0; tg < 4; ++tg)
                of[tg] = *(const half8*)(Ot_lds + (tg * 16 + l15) * 264 + ks * 32 + lhi * 8);
#pragma unroll
            for (int mt = 0; mt < 2; ++mt)
#pragma unroll
                for (int tg = 0; tg < 4; ++tg)
                    qacc[mt][tg] = MFMA16(wf[mt], of[tg], qacc[mt][tg]);
        }
#pragma unroll
        for (int mt = 0; mt < 2; ++mt) {
            float bv[4];
#pragma unroll
            for (int j = 0; j < 4; ++j) bv[j] = b2[h * 32 + mt * 16 + lhi * 4 + j];
#pragma unroll
            for (int tg = 0; tg < 4; ++tg) {
                half4 hv;
#pragma unroll
                for (int j = 0; j < 4; ++j)
                    hv[j] = (_Float16)(qacc[mt][tg][j] + bv[j]);
                qh[mt][tg] = hv;
            }
        }
    }
    __syncthreads();                               // BAR2 (Ot region freed)

    // P3a: stage V^T for this head (per-wave private region)
    {
        half8 vv[4];
#pragma unroll
        for (int i = 0; i < 4; ++i)
            vv[i] = *(const half8*)(Vsrc + kvbase + (size_t)lane * 256 + h * 32 + i * 8);
#pragma unroll
        for (int i = 0; i < 4; ++i)
#pragma unroll
            for (int j = 0; j < 8; ++j)
                Vt_h[(i * 8 + j) * 72 + lane] = vv[i][j];
    }

    // P3b: S^T via K=16 MFMA; Ks from global in K16 A-operand positions
    f32x4 st[4][4] = {};
#pragma unroll
    for (int rt = 0; rt < 4; ++rt) {
        const _Float16* kp = Ksrc + kvbase + (size_t)(rt * 16 + l15) * 256 + h * 32 + lhi * 4;
        half4 k0 = *(const half4*)(kp);
        half4 k1 = *(const half4*)(kp + 16);
#pragma unroll
        for (int g = 0; g < 4; ++g) {
            st[g][rt] = MFMA16K16(k0, qh[0][g], st[g][rt]);
            st[g][rt] = MFMA16K16(k1, qh[1][g], st[g][rt]);
        }
    }

    // P3c: softmax per q-col; st <- P
    const float scale = 0.17677669529663687f;
#pragma unroll
    for (int g = 0; g < 4; ++g) {
        float m = st[g][0][0];
#pragma unroll
        for (int rt = 0; rt < 4; ++rt)
#pragma unroll
            for (int j = 0; j < 4; ++j) m = fmaxf(m, st[g][rt][j]);
        m = fmaxf(m, __shfl_xor(m, 16));
        m = fmaxf(m, __shfl_xor(m, 32));
        float sum = 0.0f;
#pragma unroll
        for (int rt = 0; rt < 4; ++rt)
#pragma unroll
            for (int j = 0; j < 4; ++j) {
                const float p = __expf((st[g][rt][j] - m) * scale);
                st[g][rt][j] = p;
                sum += p;
            }
        sum += __shfl_xor(sum, 16);
        sum += __shfl_xor(sum, 32);
        const float inv = 1.0f / sum;
#pragma unroll
        for (int rt = 0; rt < 4; ++rt)
#pragma unroll
            for (int j = 0; j < 4; ++j) st[g][rt][j] *= inv;
    }

    // P3d: O_h = P V via K=16 MFMA (P in regs)
    f32x4 o[4][2] = {};
#pragma unroll
    for (int rt = 0; rt < 4; ++rt) {
        half4 vb[2];
#pragma unroll
        for (int dt = 0; dt < 2; ++dt)
            vb[dt] = *(const half4*)(Vt_h + (dt * 16 + l15) * 72 + rt * 16 + lhi * 4);
#pragma unroll
        for (int g = 0; g < 4; ++g) {
            half4 pa;
#pragma unroll
            for (int j = 0; j < 4; ++j) pa[j] = (_Float16)st[g][rt][j];
#pragma unroll
            for (int dt = 0; dt < 2; ++dt)
                o[g][dt] = MFMA16K16(pa, vb[dt], o[g][dt]);
        }
    }
    __syncthreads();                               // BAR3 (Vt region freed)

    // P4: O -> LDS [token][d], heads side by side
#pragma unroll
    for (int g = 0; g < 4; ++g)
#pragma unroll
        for (int dt = 0; dt < 2; ++dt)
#pragma unroll
            for (int j = 0; j < 4; ++j)
                O_lds[(g * 16 + lhi * 4 + j) * 264 + h * 32 + dt * 16 + l15] =
                    (_Float16)o[g][dt][j];
    __syncthreads();                               // BAR4

    // P5: out = O @ s_wd^T + bd; direct fp32 stores
    {
        f32x4 oc[4][2] = {};
#pragma unroll
        for (int ks = 0; ks < 8; ++ks) {
            half8 af[4], wf2[2];
#pragma unroll
            for (int g2 = 0; g2 < 4; ++g2)
                af[g2] = *(const half8*)(O_lds + (g2 * 16 + l15) * 264 + ks * 32 + lhi * 8);
#pragma unroll
            for (int nt = 0; nt < 2; ++nt)
                wf2[nt] = *(const half8*)(Wd + (size_t)(h * 32 + nt * 16 + l15) * 256 + ks * 32 + lhi * 8);
#pragma unroll
            for (int g2 = 0; g2 < 4; ++g2)
#pragma unroll
                for (int nt = 0; nt < 2; ++nt)
                    oc[g2][nt] = MFMA16(af[g2], wf2[nt], oc[g2][nt]);
        }
        const float bdv[2] = { bd[h * 32 + l15], bd[h * 32 + 16 + l15] };
        float* outb = out + kvbase;
#pragma unroll
        for (int g2 = 0; g2 < 4; ++g2)
#pragma unroll
            for (int nt = 0; nt < 2; ++nt)
#pragma unroll
                for (int j = 0; j < 4; ++j)
                    outb[(size_t)(g2 * 16 + lhi * 4 + j) * 256 +
                         h * 32 + nt * 16 + l15] = oc[g2][nt][j] + bdv[nt];
    }
}

// ---------------- host launch ----------------
extern "C" void kernel_launch(void* const* d_in, const int* in_sizes, int n_in,
                              void* d_out, int out_size, void* d_ws, size_t ws_size,
                              hipStream_t stream)
{
    const float* q    = (const float*)d_in[0];
    const float* k    = (const float*)d_in[1];
    const float* v    = (const float*)d_in[2];
    const float* t_wq = (const float*)d_in[3];
    const float* t_wk = (const float*)d_in[4];
    const float* t_wv = (const float*)d_in[5];
    const float* t_wd = (const float*)d_in[6];
    const float* t_bd = (const float*)d_in[7];
    const float* s_wq = (const float*)d_in[8];
    const float* s_wk = (const float*)d_in[9];
    const float* s_wv = (const float*)d_in[10];
    const float* s_wd = (const float*)d_in[11];
    const float* s_bd = (const float*)d_in[12];

    // workspace: 7 fp16 weight slots + b2 (fp32) + 6 activation slots (32 MB)
    _Float16* Wb = (_Float16*)d_ws;
    float* b2 = (float*)(Wb + 7 * 65536);
    const size_t SLOT = (size_t)65536 * 256;
    _Float16* S0 = (_Float16*)(b2 + 256);   // Ot (NL)
    _Float16* S1 = S0 + SLOT;               // Qt (NL)
    _Float16* S2 = S0 + 2 * SLOT;           // Kt (NL)
    _Float16* S3 = S0 + 3 * SLOT;           // Vt (NL)
    _Float16* S4 = S0 + 4 * SLOT;           // Ks (LN)
    _Float16* S5 = S0 + 5 * SLOT;           // Vs (LN)

    prep_weights<<<1792, 256, 0, stream>>>(
        t_wq, t_wk, s_wk, t_wv, s_wv, s_wd, s_wq, t_wd, t_bd, Wb, b2);

    // all five projections in one persistent dispatch
    gemm_penta<<<256, 512, 0, stream>>>(q, k, v, Wb, S1, S2, S3, S4, S5);

    attn_temporal<<<4096, 256, 0, stream>>>(S1, S2, S3, S0);   // Ot(NL) -> S0

    attn_social_fused<<<1024, 512, 0, stream>>>(
        S0, S4, S5, Wb + 5 * 65536, b2, Wb + 6 * 65536, s_bd, (float*)d_out);

    (void)in_sizes; (void)n_in; (void)out_size; (void)ws_size;
}

// Round 18
// 258.342 us; speedup vs baseline: 1.4401x; 1.4401x over previous
//
#include <hip/hip_runtime.h>

typedef __attribute__((ext_vector_type(8))) _Float16 half8;
typedef __attribute__((ext_vector_type(4))) _Float16 half4;
typedef __attribute__((ext_vector_type(4))) float f32x4;

#define MFMA16(a, b, c) __builtin_amdgcn_mfma_f32_16x16x32_f16((a), (b), (c), 0, 0, 0)
#define MFMA16K16(a, b, c) __builtin_amdgcn_mfma_f32_16x16x16f16((a), (b), (c), 0, 0, 0)

#define WAITV(N) asm volatile("s_waitcnt vmcnt(" #N ") lgkmcnt(0)" ::: "memory")
#define WAITL()  asm volatile("s_waitcnt lgkmcnt(0)" ::: "memory")
#define SBAR()   asm volatile("s_barrier" ::: "memory")

// B=8, L=128, N=64, D=256, H=8, dk=32.  M = 65536 tokens.
// Token orders: LN = (b,l,n), NL = (b,n,l).

__device__ inline int map_ln_nl(int t) {   // (b,l,n) -> (b,n,l)
    return (t & ~8191) | ((t & 63) << 7) | ((t >> 6) & 127);
}

typedef const __attribute__((address_space(1))) unsigned int guint;
typedef __attribute__((address_space(3))) unsigned int luint;
__device__ inline void gld16(const _Float16* g, _Float16* l) {
    __builtin_amdgcn_global_load_lds((guint*)g, (luint*)l, 16, 0, 0);
}

// ---------------- weight prep (single dispatch): fp32->fp16 cvt + W2/b2 ----------------
// slots: 0=t_wq 1=t_wk 2=s_wk 3=t_wv 4=s_wv 5=W2 6=s_wd
__global__ __launch_bounds__(256) void prep_weights(
    const float* __restrict__ t_wq, const float* __restrict__ t_wk,
    const float* __restrict__ s_wk, const float* __restrict__ t_wv,
    const float* __restrict__ s_wv, const float* __restrict__ s_wd,
    const float* __restrict__ s_wq, const float* __restrict__ t_wd,
    const float* __restrict__ t_bd, _Float16* __restrict__ Wb,
    float* __restrict__ b2)
{
    const int bx = blockIdx.x;
    if (bx < 1536) {
        const float* src[6] = {t_wq, t_wk, s_wk, t_wv, s_wv, s_wd};
        const int m = bx >> 8;
        const int slot = (m < 5) ? m : 6;
        const int i = (bx & 255) * 256 + threadIdx.x;
        Wb[(size_t)slot * 65536 + i] = (_Float16)src[m][i];
    } else {
        const int e = bx - 1536;
        const int d = threadIdx.x;
        float acc = 0.0f;
        for (int c = 0; c < 256; ++c)
            acc = fmaf(s_wq[e * 256 + c], t_wd[c * 256 + d], acc);
        Wb[5 * 65536 + e * 256 + d] = (_Float16)acc;
        if (d == 0) {
            float bb = 0.0f;
            for (int c = 0; c < 256; ++c) bb = fmaf(s_wq[e * 256 + c], t_bd[c], bb);
            b2[e] = bb;
        }
    }
}

// ---------------- penta GEMM v2b: 2 blocks/CU, NO VGPR cap ----------------
// 512 blocks x 5 jobs; block owns one 128-row m-tile (XCD-swizzled), jobs:
// 0 Qt(NL) 1 Kt(NL) 2 Ks(LN) 3 Vt(NL) 4 Vs(LN).  20 K-steps continuous.
// LDS 80 KB: A single 16 KB (epilogue reuses as Cst), B dbuf 64 KB ->
// 2 blocks/CU at VGPR<=128.  __launch_bounds__(512,2): R14/R15's (512,4)
// capped VGPR at 128 -> compiler SPILLS -> scratch VMEM ops entered the
// vmcnt FIFO -> hand-counted waits raced (root cause of both failures,
// confirmed by R17's spill signature: +330MB writes, LDS inflation).
// vmcnt FIFO (all 20 steps traced): steady top = [B(s),A(s+1)] = 8; step
// issues +8 -> WAITV(12) retires B(s).  Post-epilogue (s%4==0, s>0): st8 in
// FIFO -> WAITV(20).  s=18: issueA(20) absent -> WAITV(8).  s=19: WAITV(0).
__global__ __launch_bounds__(512, 2) void gemm_penta(
    const float* __restrict__ q, const float* __restrict__ k,
    const float* __restrict__ v, const _Float16* __restrict__ Wb,
    _Float16* __restrict__ Qt, _Float16* __restrict__ Kt,
    _Float16* __restrict__ Vt, _Float16* __restrict__ Ks,
    _Float16* __restrict__ Vs)
{
    __shared__ __align__(16) _Float16 lds[40960];   // 80 KB

    const int tid  = threadIdx.x;
    const int lane = tid & 63;
    const int l15  = lane & 15;
    const int lhi  = lane >> 4;
    const int wid  = tid >> 6;
    const int wg   = (blockIdx.x & 7) * 64 + (blockIdx.x >> 3);   // 512 blocks
    const int m0   = wg * 128;
    const int wr   = (wid >> 2) * 64;
    const int wc   = (wid & 3) * 64;

    int rA[2], cA[2];
#pragma unroll
    for (int i = 0; i < 2; ++i) {
        const int c = i * 512 + tid;
        rA[i] = c >> 3; cA[i] = ((c & 7) ^ (rA[i] & 7)) * 8;
    }
    int rB[4], cB[4];
#pragma unroll
    for (int i = 0; i < 4; ++i) {
        const int c = i * 512 + tid;
        rB[i] = c >> 3; cB[i] = ((c & 7) ^ (rB[i] & 7)) * 8;
    }

    f32x4 arE[2][2], arO[2][2];

    auto issueA = [&](int s, f32x4 (&dst)[2][2]) {
        const int w = s >> 2;
        const float* A = (w == 0) ? q : (w < 3 ? k : v);
        const int k0 = (s & 3) * 64;
#pragma unroll
        for (int i = 0; i < 2; ++i) {
            const float* p = A + (size_t)(m0 + rA[i]) * 256 + k0 + cA[i];
            dst[i][0] = *(const f32x4*)(p);
            dst[i][1] = *(const f32x4*)(p + 4);
        }
    };
    auto stageB = [&](int s) {
        const _Float16* W = Wb + (size_t)(s >> 2) * 65536;
        _Float16* Bd = lds + 8192 + (s & 1) * 16384;
        const int k0 = (s & 3) * 64;
#pragma unroll
        for (int i = 0; i < 4; ++i)
            gld16(W + (size_t)rB[i] * 256 + k0 + cB[i], Bd + (i * 512 + tid) * 8);
    };
    auto writeA = [&](const f32x4 (&src)[2][2]) {
#pragma unroll
        for (int i = 0; i < 2; ++i) {
            half8 h;
#pragma unroll
            for (int r2 = 0; r2 < 4; ++r2) {
                h[r2]     = (_Float16)src[i][0][r2];
                h[4 + r2] = (_Float16)src[i][1][r2];
            }
            *(half8*)(lds + (i * 512 + tid) * 8) = h;
        }
    };

    f32x4 acc[4][4] = {};

    auto mfmaStep = [&](int s) {
        const _Float16* Ab = lds;
        const _Float16* Bb = lds + 8192 + (s & 1) * 16384;
#pragma unroll
        for (int kk = 0; kk < 2; ++kk) {
            half8 af[4], bf[4];
#pragma unroll
            for (int mi = 0; mi < 4; ++mi) {
                const int R = wr + mi * 16 + l15;
                af[mi] = *(const half8*)(Ab + R * 64 + (((kk * 4 + lhi) ^ (R & 7)) * 8));
            }
#pragma unroll
            for (int nj = 0; nj < 4; ++nj) {
                const int R = wc + nj * 16 + l15;
                bf[nj] = *(const half8*)(Bb + R * 64 + (((kk * 4 + lhi) ^ (R & 7)) * 8));
            }
#pragma unroll
            for (int mi = 0; mi < 4; ++mi)
#pragma unroll
                for (int nj = 0; nj < 4; ++nj)
                    acc[mi][nj] = MFMA16(af[mi], bf[nj], acc[mi][nj]);
        }
    };

    // epilogue: Cst aliases A-buf ([32][256] chunk-XOR-swizzled), 4 passes.
    auto epilogue = [&](int w) {
        _Float16* Cp; bool nl;
        if (w == 0)      { Cp = Qt; nl = true;  }
        else if (w == 1) { Cp = Kt; nl = true;  }
        else if (w == 2) { Cp = Ks; nl = false; }
        else if (w == 3) { Cp = Vt; nl = true;  }
        else             { Cp = Vs; nl = false; }
        _Float16* Cst = lds;
        const int wgrp = wid >> 2;
#pragma unroll
        for (int c = 0; c < 4; ++c) {
            if (wgrp == (c >> 1)) {
                const int mib = (c & 1) * 2;
#pragma unroll
                for (int mi2 = 0; mi2 < 2; ++mi2) {
#pragma unroll
                    for (int nj = 0; nj < 4; ++nj) {
                        const int col = wc + nj * 16 + l15;
#pragma unroll
                        for (int j = 0; j < 4; ++j) {
                            const int rip = mi2 * 16 + lhi * 4 + j;
                            Cst[rip * 256 +
                                ((((col >> 3) ^ (rip & 7)) << 3) | (col & 7))] =
                                (_Float16)acc[mib + mi2][nj][j];
                        }
                    }
                }
            }
            WAITL(); SBAR();
            const int r  = tid >> 4;
            const int cg = tid & 15;
            const int grow = m0 + c * 32 + r;
            const int orow = nl ? map_ln_nl(grow) : grow;
            _Float16* dst = Cp + (size_t)orow * 256 + cg * 16;
#pragma unroll
            for (int u = 0; u < 2; ++u) {
                half8 hv = *(const half8*)(Cst + r * 256 +
                                           (((cg * 2 + u) ^ (r & 7)) << 3));
                *(half8*)(dst + u * 8) = hv;
            }
            SBAR();
        }
#pragma unroll
        for (int mi = 0; mi < 4; ++mi)
#pragma unroll
            for (int nj = 0; nj < 4; ++nj)
                acc[mi][nj] = (f32x4){0.f, 0.f, 0.f, 0.f};
    };

    // prologue
    issueA(0, arE); stageB(0); issueA(1, arO); writeA(arE);

    for (int s = 0; s < 20; ++s) {
        if (s + 1 < 20) stageB(s + 1);
        if (s + 2 < 20) issueA(s + 2, (s & 1) ? arO : arE);   // parity of (s+2)
        if (s == 19)                   { WAITV(0);  }
        else if (s == 18)              { WAITV(8);  }   // issueA(20) absent
        else if ((s & 3) == 0 && s)    { WAITV(20); }   // epilogue st8 in FIFO
        else                           { WAITV(12); }
        SBAR();
        mfmaStep(s);
        SBAR();
        if ((s & 3) == 3) epilogue(s >> 2);
        if (s + 1 < 20) writeA(((s + 1) & 1) ? arO : arE);
    }
}

// ---------------- temporal attention: per (b,n,h), seq = L = 128, NL layout ----------------
// XCD-swizzled blockIdx (bijective, 4096 = 8*512).
__global__ __launch_bounds__(256) void attn_temporal(
    const _Float16* __restrict__ Q, const _Float16* __restrict__ K,
    const _Float16* __restrict__ V, _Float16* __restrict__ O)
{
    __shared__ __align__(16) _Float16 Vt[32][136];   // V^T: [d][l]

    const int tid  = threadIdx.x;
    const int lane = tid & 63;
    const int l15  = lane & 15;
    const int lhi  = lane >> 4;
    const int wid  = tid >> 6;
    const int bidx = (blockIdx.x & 7) * 512 + (blockIdx.x >> 3);
    const int h = bidx & 7;
    const int n = (bidx >> 3) & 63;
    const int b = bidx >> 9;
    const size_t base = ((size_t)(b * 64 + n) * 128) * 256 + (size_t)h * 32;

    {
        const int l  = tid >> 1;
        const int dh = (tid & 1) * 16;
        const _Float16* srcp = V + base + (size_t)l * 256 + dh;
        half8 v0 = *(const half8*)(srcp);
        half8 v1 = *(const half8*)(srcp + 8);
#pragma unroll
        for (int j = 0; j < 8; ++j) {
            Vt[dh + j][l]     = v0[j];
            Vt[dh + 8 + j][l] = v1[j];
        }
    }
    __syncthreads();

    half8 qf[2];
#pragma unroll
    for (int ct = 0; ct < 2; ++ct)
        qf[ct] = *(const half8*)(Q + base +
                  (size_t)(wid * 32 + ct * 16 + l15) * 256 + lhi * 8);
    f32x4 st[2][8] = {};
#pragma unroll
    for (int rt = 0; rt < 8; ++rt) {
        half8 kf = *(const half8*)(K + base +
                    (size_t)(rt * 16 + l15) * 256 + lhi * 8);
#pragma unroll
        for (int ct = 0; ct < 2; ++ct)
            st[ct][rt] = MFMA16(kf, qf[ct], st[ct][rt]);
    }

    const float scale = 0.17677669529663687f;  // 1/sqrt(32)
#pragma unroll
    for (int ct = 0; ct < 2; ++ct) {
        float m = st[ct][0][0];
#pragma unroll
        for (int rt = 0; rt < 8; ++rt)
#pragma unroll
            for (int j = 0; j < 4; ++j) m = fmaxf(m, st[ct][rt][j]);
        m = fmaxf(m, __shfl_xor(m, 16));
        m = fmaxf(m, __shfl_xor(m, 32));
        float sum = 0.0f;
#pragma unroll
        for (int rt = 0; rt < 8; ++rt)
#pragma unroll
            for (int j = 0; j < 4; ++j) {
                const float p = __expf((st[ct][rt][j] - m) * scale);
                st[ct][rt][j] = p;
                sum += p;
            }
        sum += __shfl_xor(sum, 16);
        sum += __shfl_xor(sum, 32);
        const float inv = 1.0f / sum;
#pragma unroll
        for (int rt = 0; rt < 8; ++rt)
#pragma unroll
            for (int j = 0; j < 4; ++j) st[ct][rt][j] *= inv;
    }

    f32x4 o[2][2] = {};
#pragma unroll
    for (int rt = 0; rt < 8; ++rt) {
        half4 pa[2];
#pragma unroll
        for (int ct = 0; ct < 2; ++ct) {
            half4 tt;
#pragma unroll
            for (int j = 0; j < 4; ++j) tt[j] = (_Float16)st[ct][rt][j];
            pa[ct] = tt;
        }
#pragma unroll
        for (int dt = 0; dt < 2; ++dt) {
            half4 vb = *(const half4*)(&Vt[dt * 16 + l15][rt * 16 + lhi * 4]);
#pragma unroll
            for (int ct = 0; ct < 2; ++ct)
                o[ct][dt] = MFMA16K16(pa[ct], vb, o[ct][dt]);
        }
    }
#pragma unroll
    for (int ct = 0; ct < 2; ++ct)
#pragma unroll
        for (int dt = 0; dt < 2; ++dt)
#pragma unroll
            for (int j = 0; j < 4; ++j)
                O[base + (size_t)(wid * 32 + ct * 16 + lhi * 4 + j) * 256 +
                  dt * 16 + l15] = (_Float16)o[ct][dt][j];
}

// ---------------- fused social stage: per (b,l), 8 waves = 8 heads (R13) ----------------
__global__ __launch_bounds__(512, 4) void attn_social_fused(
    const _Float16* __restrict__ Ot,   // NL (b,n,l,d) fp16
    const _Float16* __restrict__ Ksrc, // LN fp16
    const _Float16* __restrict__ Vsrc, // LN fp16
    const _Float16* __restrict__ W2, const float* __restrict__ b2,
    const _Float16* __restrict__ Wd, const float* __restrict__ bd,
    float* __restrict__ out)           // LN fp32
{
    __shared__ __align__(16) _Float16 lds[18432];   // 36 KB

    const int tid  = threadIdx.x;
    const int lane = tid & 63;
    const int l15  = lane & 15;
    const int lhi  = lane >> 4;
    const int h    = tid >> 6;          // wave = head
    const int l = blockIdx.x & 127;
    const int b = blockIdx.x >> 7;

    _Float16* Ot_lds = lds;                        // [64][264]
    _Float16* Vt_h   = lds + h * 2304;             // [32][72] (after BAR2)
    _Float16* O_lds  = lds;                        // [64][264] (after BAR3)

    const size_t kvbase = ((size_t)(b * 128 + l) * 64) * 256;

    // P1: stage Ot slice (coalesced 512B rows)
#pragma unroll
    for (int i = 0; i < 4; ++i) {
        const int chunk = i * 512 + tid;
        const int r  = chunk >> 5;
        const int c8 = (chunk & 31) * 8;
        half8 vv = *(const half8*)(Ot + ((size_t)(b * 64 + r) * 128 + l) * 256 + c8);
        *(half8*)(Ot_lds + r * 264 + c8) = vv;
    }
    __syncthreads();                               // BAR1

    // P2: Qs = Ot @ W2_h^T + b2_h -> qh[mt][g] REGISTERS ONLY
    half4 qh[2][4];
    {
        f32x4 qacc[2][4] = {};
#pragma unroll
        for (int ks = 0; ks < 8; ++ks) {
            half8 wf[2], of[4];
#pragma unroll
            for (int mt = 0; mt < 2; ++mt)
                wf[mt] = *(const half8*)(W2 + (size_t)(h * 32 + mt * 16 + l15) * 256 + ks * 32 + lhi * 8);
#pragma unroll
            for (int tg = 0; tg < 4; ++tg)
                of[tg] = *(const half8*)(Ot_lds + (tg * 16 + l15) * 264 + ks * 32 + lhi * 8);
#pragma unroll
            for (int mt = 0; mt < 2; ++mt)
#pragma unroll
                for (int tg = 0; tg < 4; ++tg)
                    qacc[mt][tg] = MFMA16(wf[mt], of[tg], qacc[mt][tg]);
        }
#pragma unroll
        for (int mt = 0; mt < 2; ++mt) {
            float bv[4];
#pragma unroll
            for (int j = 0; j < 4; ++j) bv[j] = b2[h * 32 + mt * 16 + lhi * 4 + j];
#pragma unroll
            for (int tg = 0; tg < 4; ++tg) {
                half4 hv;
#pragma unroll
                for (int j = 0; j < 4; ++j)
                    hv[j] = (_Float16)(qacc[mt][tg][j] + bv[j]);
                qh[mt][tg] = hv;
            }
        }
    }
    __syncthreads();                               // BAR2 (Ot region freed)

    // P3a: stage V^T for this head (per-wave private region)
    {
        half8 vv[4];
#pragma unroll
        for (int i = 0; i < 4; ++i)
            vv[i] = *(const half8*)(Vsrc + kvbase + (size_t)lane * 256 + h * 32 + i * 8);
#pragma unroll
        for (int i = 0; i < 4; ++i)
#pragma unroll
            for (int j = 0; j < 8; ++j)
                Vt_h[(i * 8 + j) * 72 + lane] = vv[i][j];
    }

    // P3b: S^T via K=16 MFMA; Ks from global in K16 A-operand positions
    f32x4 st[4][4] = {};
#pragma unroll
    for (int rt = 0; rt < 4; ++rt) {
        const _Float16* kp = Ksrc + kvbase + (size_t)(rt * 16 + l15) * 256 + h * 32 + lhi * 4;
        half4 k0 = *(const half4*)(kp);
        half4 k1 = *(const half4*)(kp + 16);
#pragma unroll
        for (int g = 0; g < 4; ++g) {
            st[g][rt] = MFMA16K16(k0, qh[0][g], st[g][rt]);
            st[g][rt] = MFMA16K16(k1, qh[1][g], st[g][rt]);
        }
    }

    // P3c: softmax per q-col; st <- P
    const float scale = 0.17677669529663687f;
#pragma unroll
    for (int g = 0; g < 4; ++g) {
        float m = st[g][0][0];
#pragma unroll
        for (int rt = 0; rt < 4; ++rt)
#pragma unroll
            for (int j = 0; j < 4; ++j) m = fmaxf(m, st[g][rt][j]);
        m = fmaxf(m, __shfl_xor(m, 16));
        m = fmaxf(m, __shfl_xor(m, 32));
        float sum = 0.0f;
#pragma unroll
        for (int rt = 0; rt < 4; ++rt)
#pragma unroll
            for (int j = 0; j < 4; ++j) {
                const float p = __expf((st[g][rt][j] - m) * scale);
                st[g][rt][j] = p;
                sum += p;
            }
        sum += __shfl_xor(sum, 16);
        sum += __shfl_xor(sum, 32);
        const float inv = 1.0f / sum;
#pragma unroll
        for (int rt = 0; rt < 4; ++rt)
#pragma unroll
            for (int j = 0; j < 4; ++j) st[g][rt][j] *= inv;
    }

    // P3d: O_h = P V via K=16 MFMA (P in regs)
    f32x4 o[4][2] = {};
#pragma unroll
    for (int rt = 0; rt < 4; ++rt) {
        half4 vb[2];
#pragma unroll
        for (int dt = 0; dt < 2; ++dt)
            vb[dt] = *(const half4*)(Vt_h + (dt * 16 + l15) * 72 + rt * 16 + lhi * 4);
#pragma unroll
        for (int g = 0; g < 4; ++g) {
            half4 pa;
#pragma unroll
            for (int j = 0; j < 4; ++j) pa[j] = (_Float16)st[g][rt][j];
#pragma unroll
            for (int dt = 0; dt < 2; ++dt)
                o[g][dt] = MFMA16K16(pa, vb[dt], o[g][dt]);
        }
    }
    __syncthreads();                               // BAR3 (Vt region freed)

    // P4: O -> LDS [token][d], heads side by side
#pragma unroll
    for (int g = 0; g < 4; ++g)
#pragma unroll
        for (int dt = 0; dt < 2; ++dt)
#pragma unroll
            for (int j = 0; j < 4; ++j)
                O_lds[(g * 16 + lhi * 4 + j) * 264 + h * 32 + dt * 16 + l15] =
                    (_Float16)o[g][dt][j];
    __syncthreads();                               // BAR4

    // P5: out = O @ s_wd^T + bd; direct fp32 stores
    {
        f32x4 oc[4][2] = {};
#pragma unroll
        for (int ks = 0; ks < 8; ++ks) {
            half8 af[4], wf2[2];
#pragma unroll
            for (int g2 = 0; g2 < 4; ++g2)
                af[g2] = *(const half8*)(O_lds + (g2 * 16 + l15) * 264 + ks * 32 + lhi * 8);
#pragma unroll
            for (int nt = 0; nt < 2; ++nt)
                wf2[nt] = *(const half8*)(Wd + (size_t)(h * 32 + nt * 16 + l15) * 256 + ks * 32 + lhi * 8);
#pragma unroll
            for (int g2 = 0; g2 < 4; ++g2)
#pragma unroll
                for (int nt = 0; nt < 2; ++nt)
                    oc[g2][nt] = MFMA16(af[g2], wf2[nt], oc[g2][nt]);
        }
        const float bdv[2] = { bd[h * 32 + l15], bd[h * 32 + 16 + l15] };
        float* outb = out + kvbase;
#pragma unroll
        for (int g2 = 0; g2 < 4; ++g2)
#pragma unroll
            for (int nt = 0; nt < 2; ++nt)
#pragma unroll
                for (int j = 0; j < 4; ++j)
                    outb[(size_t)(g2 * 16 + lhi * 4 + j) * 256 +
                         h * 32 + nt * 16 + l15] = oc[g2][nt][j] + bdv[nt];
    }
}

// ---------------- host launch ----------------
extern "C" void kernel_launch(void* const* d_in, const int* in_sizes, int n_in,
                              void* d_out, int out_size, void* d_ws, size_t ws_size,
                              hipStream_t stream)
{
    const float* q    = (const float*)d_in[0];
    const float* k    = (const float*)d_in[1];
    const float* v    = (const float*)d_in[2];
    const float* t_wq = (const float*)d_in[3];
    const float* t_wk = (const float*)d_in[4];
    const float* t_wv = (const float*)d_in[5];
    const float* t_wd = (const float*)d_in[6];
    const float* t_bd = (const float*)d_in[7];
    const float* s_wq = (const float*)d_in[8];
    const float* s_wk = (const float*)d_in[9];
    const float* s_wv = (const float*)d_in[10];
    const float* s_wd = (const float*)d_in[11];
    const float* s_bd = (const float*)d_in[12];

    // workspace: 7 fp16 weight slots + b2 (fp32) + 6 activation slots (32 MB)
    _Float16* Wb = (_Float16*)d_ws;
    float* b2 = (float*)(Wb + 7 * 65536);
    const size_t SLOT = (size_t)65536 * 256;
    _Float16* S0 = (_Float16*)(b2 + 256);   // Ot (NL)
    _Float16* S1 = S0 + SLOT;               // Qt (NL)
    _Float16* S2 = S0 + 2 * SLOT;           // Kt (NL)
    _Float16* S3 = S0 + 3 * SLOT;           // Vt (NL)
    _Float16* S4 = S0 + 4 * SLOT;           // Ks (LN)
    _Float16* S5 = S0 + 5 * SLOT;           // Vs (LN)

    prep_weights<<<1792, 256, 0, stream>>>(
        t_wq, t_wk, s_wk, t_wv, s_wv, s_wd, s_wq, t_wd, t_bd, Wb, b2);

    // all five projections in one persistent dispatch (2 blocks/CU)
    gemm_penta<<<512, 512, 0, stream>>>(q, k, v, Wb, S1, S2, S3, S4, S5);

    attn_temporal<<<4096, 256, 0, stream>>>(S1, S2, S3, S0);   // Ot(NL) -> S0

    attn_social_fused<<<1024, 512, 0, stream>>>(
        S0, S4, S5, Wb + 5 * 65536, b2, Wb + 6 * 65536, s_bd, (float*)d_out);

    (void)in_sizes; (void)n_in; (void)out_size; (void)ws_size;
}

// Round 19
// 253.360 us; speedup vs baseline: 1.4685x; 1.0197x over previous
//
#include <hip/hip_runtime.h>

typedef __attribute__((ext_vector_type(8))) _Float16 half8;
typedef __attribute__((ext_vector_type(4))) _Float16 half4;
typedef __attribute__((ext_vector_type(4))) float f32x4;

#define MFMA16(a, b, c) __builtin_amdgcn_mfma_f32_16x16x32_f16((a), (b), (c), 0, 0, 0)
#define MFMA16K16(a, b, c) __builtin_amdgcn_mfma_f32_16x16x16f16((a), (b), (c), 0, 0, 0)

#define WAITV(N) asm volatile("s_waitcnt vmcnt(" #N ") lgkmcnt(0)" ::: "memory")
#define WAITL()  asm volatile("s_waitcnt lgkmcnt(0)" ::: "memory")
#define SBAR()   asm volatile("s_barrier" ::: "memory")

// B=8, L=128, N=64, D=256, H=8, dk=32.  M = 65536 tokens.
// Token orders: LN = (b,l,n), NL = (b,n,l).

__device__ inline int map_ln_nl(int t) {   // (b,l,n) -> (b,n,l)
    return (t & ~8191) | ((t & 63) << 7) | ((t >> 6) & 127);
}

typedef const __attribute__((address_space(1))) unsigned int guint;
typedef __attribute__((address_space(3))) unsigned int luint;
__device__ inline void gld16(const _Float16* g, _Float16* l) {
    __builtin_amdgcn_global_load_lds((guint*)g, (luint*)l, 16, 0, 0);
}

// ---------------- weight prep (single dispatch): fp32->fp16 cvt + W2/b2 ----------------
// slots: 0=t_wq 1=t_wk 2=s_wk 3=t_wv 4=s_wv 5=W2 6=s_wd
__global__ __launch_bounds__(256) void prep_weights(
    const float* __restrict__ t_wq, const float* __restrict__ t_wk,
    const float* __restrict__ s_wk, const float* __restrict__ t_wv,
    const float* __restrict__ s_wv, const float* __restrict__ s_wd,
    const float* __restrict__ s_wq, const float* __restrict__ t_wd,
    const float* __restrict__ t_bd, _Float16* __restrict__ Wb,
    float* __restrict__ b2)
{
    const int bx = blockIdx.x;
    if (bx < 1536) {
        const float* src[6] = {t_wq, t_wk, s_wk, t_wv, s_wv, s_wd};
        const int m = bx >> 8;
        const int slot = (m < 5) ? m : 6;
        const int i = (bx & 255) * 256 + threadIdx.x;
        Wb[(size_t)slot * 65536 + i] = (_Float16)src[m][i];
    } else {
        const int e = bx - 1536;
        const int d = threadIdx.x;
        float acc = 0.0f;
        for (int c = 0; c < 256; ++c)
            acc = fmaf(s_wq[e * 256 + c], t_wd[c * 256 + d], acc);
        Wb[5 * 65536 + e * 256 + d] = (_Float16)acc;
        if (d == 0) {
            float bb = 0.0f;
            for (int c = 0; c < 256; ++c) bb = fmaf(s_wq[e * 256 + c], t_bd[c], bb);
            b2[e] = bb;
        }
    }
}

// ---------------- penta GEMM: persistent, cross-tile pipelined (R13/R16-proven) ----------------
// 256 blocks (1/CU) x 10 jobs each.  Job = 128x256 tile of one of 5 outputs:
// which = job%5: 0 Qt=q@t_wq^T(NL) 1 Kt=k@t_wk^T(NL) 2 Ks=k@s_wk^T(LN)
//                3 Vt=v@t_wv^T(NL) 4 Vs=v@s_wv^T(LN);  mtile = job/5.
// 40 K-steps, one continuous stream: B gld16 dbuf, A fp32 reg-staged 2 deep,
// counted vmcnt (12/20/8, 0 only at step 39), raw s_barrier.
// NOTE: counted-vmcnt schedules require ZERO compiler VMEM ops — no
// __launch_bounds__ VGPR cap (spills would corrupt the FIFO count; R14-R17).
__global__ __launch_bounds__(512, 2) void gemm_penta(
    const float* __restrict__ q, const float* __restrict__ k,
    const float* __restrict__ v, const _Float16* __restrict__ Wb,
    _Float16* __restrict__ Qt, _Float16* __restrict__ Kt,
    _Float16* __restrict__ Vt, _Float16* __restrict__ Ks,
    _Float16* __restrict__ Vs)
{
    __shared__ __align__(16) _Float16 lds[66048];

    const int tid  = threadIdx.x;
    const int lane = tid & 63;
    const int l15  = lane & 15;
    const int lhi  = lane >> 4;
    const int wid  = tid >> 6;
    const int bid  = blockIdx.x;
    const int wr   = (wid >> 2) * 64;
    const int wc   = (wid & 3) * 64;

    int rA[2], cA[2];
#pragma unroll
    for (int i = 0; i < 2; ++i) {
        const int c = i * 512 + tid;
        rA[i] = c >> 3; cA[i] = ((c & 7) ^ (rA[i] & 7)) * 8;
    }
    int rB[4], cB[4];
#pragma unroll
    for (int i = 0; i < 4; ++i) {
        const int c = i * 512 + tid;
        rB[i] = c >> 3; cB[i] = ((c & 7) ^ (rB[i] & 7)) * 8;
    }

    f32x4 arE[2][2], arO[2][2];

    auto issueA = [&](int s, f32x4 (&dst)[2][2]) {
        const int jj = s >> 2;
        const int w  = jj - (jj / 5) * 5;
        const float* A = (w == 0) ? q : (w < 3 ? k : v);
        const int m0 = (2 * bid + jj / 5) * 128;
        const int k0 = (s & 3) * 64;
#pragma unroll
        for (int i = 0; i < 2; ++i) {
            const float* p = A + (size_t)(m0 + rA[i]) * 256 + k0 + cA[i];
            dst[i][0] = *(const f32x4*)(p);
            dst[i][1] = *(const f32x4*)(p + 4);
        }
    };
    auto stageB = [&](int s) {
        const int jj = s >> 2;
        const _Float16* W = Wb + (size_t)(jj - (jj / 5) * 5) * 65536;
        _Float16* Bd = lds + 16384 + (s & 1) * 16384;
        const int k0 = (s & 3) * 64;
#pragma unroll
        for (int i = 0; i < 4; ++i)
            gld16(W + (size_t)rB[i] * 256 + k0 + cB[i], Bd + (i * 512 + tid) * 8);
    };
    auto writeA = [&](int s, const f32x4 (&src)[2][2]) {
        _Float16* Ad = lds + (s & 1) * 8192;
#pragma unroll
        for (int i = 0; i < 2; ++i) {
            half8 h;
#pragma unroll
            for (int r2 = 0; r2 < 4; ++r2) {
                h[r2]     = (_Float16)src[i][0][r2];
                h[4 + r2] = (_Float16)src[i][1][r2];
            }
            *(half8*)(Ad + (i * 512 + tid) * 8) = h;
        }
    };

    f32x4 acc[4][4] = {};

    auto mfmaStep = [&](int s) {
        const _Float16* Ab = lds + (s & 1) * 8192;
        const _Float16* Bb = lds + 16384 + (s & 1) * 16384;
#pragma unroll
        for (int kk = 0; kk < 2; ++kk) {
            half8 af[4], bf[4];
#pragma unroll
            for (int mi = 0; mi < 4; ++mi) {
                const int R = wr + mi * 16 + l15;
                af[mi] = *(const half8*)(Ab + R * 64 + (((kk * 4 + lhi) ^ (R & 7)) * 8));
            }
#pragma unroll
            for (int nj = 0; nj < 4; ++nj) {
                const int R = wc + nj * 16 + l15;
                bf[nj] = *(const half8*)(Bb + R * 64 + (((kk * 4 + lhi) ^ (R & 7)) * 8));
            }
#pragma unroll
            for (int mi = 0; mi < 4; ++mi)
#pragma unroll
                for (int nj = 0; nj < 4; ++nj)
                    acc[mi][nj] = MFMA16(af[mi], bf[nj], acc[mi][nj]);
        }
    };

    auto epilogue = [&](int jj) {
        const int w = jj - (jj / 5) * 5;
        _Float16* Cp; bool nl;
        if (w == 0)      { Cp = Qt; nl = true;  }
        else if (w == 1) { Cp = Kt; nl = true;  }
        else if (w == 2) { Cp = Ks; nl = false; }
        else if (w == 3) { Cp = Vt; nl = true;  }
        else             { Cp = Vs; nl = false; }
        const int m0 = (2 * bid + jj / 5) * 128;
        _Float16* Cst = lds + 49152;
#pragma unroll
        for (int c = 0; c < 2; ++c) {
            if ((wid >> 2) == c) {
#pragma unroll
                for (int mi = 0; mi < 4; ++mi)
#pragma unroll
                    for (int nj = 0; nj < 4; ++nj) {
                        const int col = wc + nj * 16 + l15;
#pragma unroll
                        for (int j = 0; j < 4; ++j)
                            Cst[(mi * 16 + lhi * 4 + j) * 264 + col] =
                                (_Float16)acc[mi][nj][j];
                    }
            }
            WAITL(); SBAR();
            const int r  = tid >> 3;
            const int c0 = (tid & 7) * 32;
            const int grow = m0 + c * 64 + r;
            const int orow = nl ? map_ln_nl(grow) : grow;
            _Float16* dst = Cp + (size_t)orow * 256 + c0;
            const _Float16* sp = Cst + r * 264 + c0;
#pragma unroll
            for (int u = 0; u < 4; ++u)
                *(half8*)(dst + u * 8) = *(const half8*)(sp + u * 8);
            WAITL(); SBAR();
        }
#pragma unroll
        for (int mi = 0; mi < 4; ++mi)
#pragma unroll
            for (int nj = 0; nj < 4; ++nj)
                acc[mi][nj] = (f32x4){0.f, 0.f, 0.f, 0.f};
    };

    // prologue: A(0), B(0), A(1), A(0)->LDS (auto-waits its loads)
    issueA(0, arE); stageB(0); issueA(1, arO); writeA(0, arE);

    for (int t = 0; t < 20; ++t) {
        {   // even step s = 2t
            const int s = 2 * t;
            if (s + 1 < 40) stageB(s + 1);
            if (s + 2 < 40) issueA(s + 2, arE);
            if (s == 38)                 { WAITV(8);  }
            else if ((s & 3) == 0 && s)  { WAITV(20); }
            else                         { WAITV(12); }
            SBAR();
            mfmaStep(s);
            SBAR();
            if (s + 1 < 40) writeA(s + 1, arO);
        }
        {   // odd step s = 2t+1
            const int s = 2 * t + 1;
            if (s + 1 < 40) stageB(s + 1);
            if (s + 2 < 40) issueA(s + 2, arO);
            if (s == 39) { WAITV(0); } else { WAITV(12); }
            SBAR();
            mfmaStep(s);
            SBAR();
            if (s + 1 < 40) writeA(s + 1, arE);
            if ((s & 3) == 3) epilogue(s >> 2);
        }
    }
}

// ---------------- temporal attention: per (b,n,h), seq = L = 128, NL layout ----------------
// XCD-swizzled blockIdx (bijective, 4096 = 8*512): all 8 heads of a (b,n) and
// 64 consecutive n-groups (~4 MB Q/K/V) land on ONE XCD's L2.
__global__ __launch_bounds__(256) void attn_temporal(
    const _Float16* __restrict__ Q, const _Float16* __restrict__ K,
    const _Float16* __restrict__ V, _Float16* __restrict__ O)
{
    __shared__ __align__(16) _Float16 Vt[32][136];   // V^T: [d][l]

    const int tid  = threadIdx.x;
    const int lane = tid & 63;
    const int l15  = lane & 15;
    const int lhi  = lane >> 4;
    const int wid  = tid >> 6;
    const int bidx = (blockIdx.x & 7) * 512 + (blockIdx.x >> 3);
    const int h = bidx & 7;
    const int n = (bidx >> 3) & 63;
    const int b = bidx >> 9;
    const size_t base = ((size_t)(b * 64 + n) * 128) * 256 + (size_t)h * 32;

    {
        const int l  = tid >> 1;
        const int dh = (tid & 1) * 16;
        const _Float16* srcp = V + base + (size_t)l * 256 + dh;
        half8 v0 = *(const half8*)(srcp);
        half8 v1 = *(const half8*)(srcp + 8);
#pragma unroll
        for (int j = 0; j < 8; ++j) {
            Vt[dh + j][l]     = v0[j];
            Vt[dh + 8 + j][l] = v1[j];
        }
    }
    __syncthreads();

    half8 qf[2];
#pragma unroll
    for (int ct = 0; ct < 2; ++ct)
        qf[ct] = *(const half8*)(Q + base +
                  (size_t)(wid * 32 + ct * 16 + l15) * 256 + lhi * 8);
    f32x4 st[2][8] = {};
#pragma unroll
    for (int rt = 0; rt < 8; ++rt) {
        half8 kf = *(const half8*)(K + base +
                    (size_t)(rt * 16 + l15) * 256 + lhi * 8);
#pragma unroll
        for (int ct = 0; ct < 2; ++ct)
            st[ct][rt] = MFMA16(kf, qf[ct], st[ct][rt]);
    }

    const float scale = 0.17677669529663687f;  // 1/sqrt(32)
#pragma unroll
    for (int ct = 0; ct < 2; ++ct) {
        float m = st[ct][0][0];
#pragma unroll
        for (int rt = 0; rt < 8; ++rt)
#pragma unroll
            for (int j = 0; j < 4; ++j) m = fmaxf(m, st[ct][rt][j]);
        m = fmaxf(m, __shfl_xor(m, 16));
        m = fmaxf(m, __shfl_xor(m, 32));
        float sum = 0.0f;
#pragma unroll
        for (int rt = 0; rt < 8; ++rt)
#pragma unroll
            for (int j = 0; j < 4; ++j) {
                const float p = __expf((st[ct][rt][j] - m) * scale);
                st[ct][rt][j] = p;
                sum += p;
            }
        sum += __shfl_xor(sum, 16);
        sum += __shfl_xor(sum, 32);
        const float inv = 1.0f / sum;
#pragma unroll
        for (int rt = 0; rt < 8; ++rt)
#pragma unroll
            for (int j = 0; j < 4; ++j) st[ct][rt][j] *= inv;
    }

    f32x4 o[2][2] = {};
#pragma unroll
    for (int rt = 0; rt < 8; ++rt) {
        half4 pa[2];
#pragma unroll
        for (int ct = 0; ct < 2; ++ct) {
            half4 tt;
#pragma unroll
            for (int j = 0; j < 4; ++j) tt[j] = (_Float16)st[ct][rt][j];
            pa[ct] = tt;
        }
#pragma unroll
        for (int dt = 0; dt < 2; ++dt) {
            half4 vb = *(const half4*)(&Vt[dt * 16 + l15][rt * 16 + lhi * 4]);
#pragma unroll
            for (int ct = 0; ct < 2; ++ct)
                o[ct][dt] = MFMA16K16(pa[ct], vb, o[ct][dt]);
        }
    }
#pragma unroll
    for (int ct = 0; ct < 2; ++ct)
#pragma unroll
        for (int dt = 0; dt < 2; ++dt)
#pragma unroll
            for (int j = 0; j < 4; ++j)
                O[base + (size_t)(wid * 32 + ct * 16 + lhi * 4 + j) * 256 +
                  dt * 16 + l15] = (_Float16)o[ct][dt][j];
}

// ---------------- fused social stage: per (b,l), 8 waves = 8 heads (R13) ----------------
__global__ __launch_bounds__(512, 4) void attn_social_fused(
    const _Float16* __restrict__ Ot,   // NL (b,n,l,d) fp16
    const _Float16* __restrict__ Ksrc, // LN fp16
    const _Float16* __restrict__ Vsrc, // LN fp16
    const _Float16* __restrict__ W2, const float* __restrict__ b2,
    const _Float16* __restrict__ Wd, const float* __restrict__ bd,
    float* __restrict__ out)           // LN fp32
{
    __shared__ __align__(16) _Float16 lds[18432];   // 36 KB

    const int tid  = threadIdx.x;
    const int lane = tid & 63;
    const int l15  = lane & 15;
    const int lhi  = lane >> 4;
    const int h    = tid >> 6;          // wave = head
    const int l = blockIdx.x & 127;
    const int b = blockIdx.x >> 7;

    _Float16* Ot_lds = lds;                        // [64][264]
    _Float16* Vt_h   = lds + h * 2304;             // [32][72] (after BAR2)
    _Float16* O_lds  = lds;                        // [64][264] (after BAR3)

    const size_t kvbase = ((size_t)(b * 128 + l) * 64) * 256;

    // P1: stage Ot slice (coalesced 512B rows)
#pragma unroll
    for (int i = 0; i < 4; ++i) {
        const int chunk = i * 512 + tid;
        const int r  = chunk >> 5;
        const int c8 = (chunk & 31) * 8;
        half8 vv = *(const half8*)(Ot + ((size_t)(b * 64 + r) * 128 + l) * 256 + c8);
        *(half8*)(Ot_lds + r * 264 + c8) = vv;
    }
    __syncthreads();                               // BAR1

    // P2: Qs = Ot @ W2_h^T + b2_h -> qh[mt][g] REGISTERS ONLY
    half4 qh[2][4];
    {
        f32x4 qacc[2][4] = {};
#pragma unroll
        for (int ks = 0; ks < 8; ++ks) {
            half8 wf[2], of[4];
#pragma unroll
            for (int mt = 0; mt < 2; ++mt)
                wf[mt] = *(const half8*)(W2 + (size_t)(h * 32 + mt * 16 + l15) * 256 + ks * 32 + lhi * 8);
#pragma unroll
            for (int tg = 0; tg < 4; ++tg)
                of[tg] = *(const half8*)(Ot_lds + (tg * 16 + l15) * 264 + ks * 32 + lhi * 8);
#pragma unroll
            for (int mt = 0; mt < 2; ++mt)
#pragma unroll
                for (int tg = 0; tg < 4; ++tg)
                    qacc[mt][tg] = MFMA16(wf[mt], of[tg], qacc[mt][tg]);
        }
#pragma unroll
        for (int mt = 0; mt < 2; ++mt) {
            float bv[4];
#pragma unroll
            for (int j = 0; j < 4; ++j) bv[j] = b2[h * 32 + mt * 16 + lhi * 4 + j];
#pragma unroll
            for (int tg = 0; tg < 4; ++tg) {
                half4 hv;
#pragma unroll
                for (int j = 0; j < 4; ++j)
                    hv[j] = (_Float16)(qacc[mt][tg][j] + bv[j]);
                qh[mt][tg] = hv;
            }
        }
    }
    __syncthreads();                               // BAR2 (Ot region freed)

    // P3a: stage V^T for this head (per-wave private region)
    {
        half8 vv[4];
#pragma unroll
        for (int i = 0; i < 4; ++i)
            vv[i] = *(const half8*)(Vsrc + kvbase + (size_t)lane * 256 + h * 32 + i * 8);
#pragma unroll
        for (int i = 0; i < 4; ++i)
#pragma unroll
            for (int j = 0; j < 8; ++j)
                Vt_h[(i * 8 + j) * 72 + lane] = vv[i][j];
    }

    // P3b: S^T via K=16 MFMA; Ks from global in K16 A-operand positions
    f32x4 st[4][4] = {};
#pragma unroll
    for (int rt = 0; rt < 4; ++rt) {
        const _Float16* kp = Ksrc + kvbase + (size_t)(rt * 16 + l15) * 256 + h * 32 + lhi * 4;
        half4 k0 = *(const half4*)(kp);
        half4 k1 = *(const half4*)(kp + 16);
#pragma unroll
        for (int g = 0; g < 4; ++g) {
            st[g][rt] = MFMA16K16(k0, qh[0][g], st[g][rt]);
            st[g][rt] = MFMA16K16(k1, qh[1][g], st[g][rt]);
        }
    }

    // P3c: softmax per q-col; st <- P
    const float scale = 0.17677669529663687f;
#pragma unroll
    for (int g = 0; g < 4; ++g) {
        float m = st[g][0][0];
#pragma unroll
        for (int rt = 0; rt < 4; ++rt)
#pragma unroll
            for (int j = 0; j < 4; ++j) m = fmaxf(m, st[g][rt][j]);
        m = fmaxf(m, __shfl_xor(m, 16));
        m = fmaxf(m, __shfl_xor(m, 32));
        float sum = 0.0f;
#pragma unroll
        for (int rt = 0; rt < 4; ++rt)
#pragma unroll
            for (int j = 0; j < 4; ++j) {
                const float p = __expf((st[g][rt][j] - m) * scale);
                st[g][rt][j] = p;
                sum += p;
            }
        sum += __shfl_xor(sum, 16);
        sum += __shfl_xor(sum, 32);
        const float inv = 1.0f / sum;
#pragma unroll
        for (int rt = 0; rt < 4; ++rt)
#pragma unroll
            for (int j = 0; j < 4; ++j) st[g][rt][j] *= inv;
    }

    // P3d: O_h = P V via K=16 MFMA (P in regs)
    f32x4 o[4][2] = {};
#pragma unroll
    for (int rt = 0; rt < 4; ++rt) {
        half4 vb[2];
#pragma unroll
        for (int dt = 0; dt < 2; ++dt)
            vb[dt] = *(const half4*)(Vt_h + (dt * 16 + l15) * 72 + rt * 16 + lhi * 4);
#pragma unroll
        for (int g = 0; g < 4; ++g) {
            half4 pa;
#pragma unroll
            for (int j = 0; j < 4; ++j) pa[j] = (_Float16)st[g][rt][j];
#pragma unroll
            for (int dt = 0; dt < 2; ++dt)
                o[g][dt] = MFMA16K16(pa, vb[dt], o[g][dt]);
        }
    }
    __syncthreads();                               // BAR3 (Vt region freed)

    // P4: O -> LDS [token][d], heads side by side
#pragma unroll
    for (int g = 0; g < 4; ++g)
#pragma unroll
        for (int dt = 0; dt < 2; ++dt)
#pragma unroll
            for (int j = 0; j < 4; ++j)
                O_lds[(g * 16 + lhi * 4 + j) * 264 + h * 32 + dt * 16 + l15] =
                    (_Float16)o[g][dt][j];
    __syncthreads();                               // BAR4

    // P5: out = O @ s_wd^T + bd; direct fp32 stores
    {
        f32x4 oc[4][2] = {};
#pragma unroll
        for (int ks = 0; ks < 8; ++ks) {
            half8 af[4], wf2[2];
#pragma unroll
            for (int g2 = 0; g2 < 4; ++g2)
                af[g2] = *(const half8*)(O_lds + (g2 * 16 + l15) * 264 + ks * 32 + lhi * 8);
#pragma unroll
            for (int nt = 0; nt < 2; ++nt)
                wf2[nt] = *(const half8*)(Wd + (size_t)(h * 32 + nt * 16 + l15) * 256 + ks * 32 + lhi * 8);
#pragma unroll
            for (int g2 = 0; g2 < 4; ++g2)
#pragma unroll
                for (int nt = 0; nt < 2; ++nt)
                    oc[g2][nt] = MFMA16(af[g2], wf2[nt], oc[g2][nt]);
        }
        const float bdv[2] = { bd[h * 32 + l15], bd[h * 32 + 16 + l15] };
        float* outb = out + kvbase;
#pragma unroll
        for (int g2 = 0; g2 < 4; ++g2)
#pragma unroll
            for (int nt = 0; nt < 2; ++nt)
#pragma unroll
                for (int j = 0; j < 4; ++j)
                    outb[(size_t)(g2 * 16 + lhi * 4 + j) * 256 +
                         h * 32 + nt * 16 + l15] = oc[g2][nt][j] + bdv[nt];
    }
}

// ---------------- host launch ----------------
extern "C" void kernel_launch(void* const* d_in, const int* in_sizes, int n_in,
                              void* d_out, int out_size, void* d_ws, size_t ws_size,
                              hipStream_t stream)
{
    const float* q    = (const float*)d_in[0];
    const float* k    = (const float*)d_in[1];
    const float* v    = (const float*)d_in[2];
    const float* t_wq = (const float*)d_in[3];
    const float* t_wk = (const float*)d_in[4];
    const float* t_wv = (const float*)d_in[5];
    const float* t_wd = (const float*)d_in[6];
    const float* t_bd = (const float*)d_in[7];
    const float* s_wq = (const float*)d_in[8];
    const float* s_wk = (const float*)d_in[9];
    const float* s_wv = (const float*)d_in[10];
    const float* s_wd = (const float*)d_in[11];
    const float* s_bd = (const float*)d_in[12];

    // workspace: 7 fp16 weight slots + b2 (fp32) + 6 activation slots (32 MB)
    _Float16* Wb = (_Float16*)d_ws;
    float* b2 = (float*)(Wb + 7 * 65536);
    const size_t SLOT = (size_t)65536 * 256;
    _Float16* S0 = (_Float16*)(b2 + 256);   // Ot (NL)
    _Float16* S1 = S0 + SLOT;               // Qt (NL)
    _Float16* S2 = S0 + 2 * SLOT;           // Kt (NL)
    _Float16* S3 = S0 + 3 * SLOT;           // Vt (NL)
    _Float16* S4 = S0 + 4 * SLOT;           // Ks (LN)
    _Float16* S5 = S0 + 5 * SLOT;           // Vs (LN)

    prep_weights<<<1792, 256, 0, stream>>>(
        t_wq, t_wk, s_wk, t_wv, s_wv, s_wd, s_wq, t_wd, t_bd, Wb, b2);

    // all five projections in one persistent dispatch
    gemm_penta<<<256, 512, 0, stream>>>(q, k, v, Wb, S1, S2, S3, S4, S5);

    attn_temporal<<<4096, 256, 0, stream>>>(S1, S2, S3, S0);   // Ot(NL) -> S0

    attn_social_fused<<<1024, 512, 0, stream>>>(
        S0, S4, S5, Wb + 5 * 65536, b2, Wb + 6 * 65536, s_bd, (float*)d_out);

    (void)in_sizes; (void)n_in; (void)out_size; (void)ws_size;
}